// Round 12
// baseline (214.173 us; speedup 1.0000x reference)
//
#include <hip/hip_runtime.h>

#define CDIM 128
#define NC   8388608

typedef __attribute__((ext_vector_type(8)))  short bf8v;   // 8 bf16 (4 VGPRs)
typedef __attribute__((ext_vector_type(16))) float f32x16; // MFMA 32x32 acc

// ws layout (float offsets):
//   nrm  @0       (1024)
//   DT   @1024    (122880)
//   Bph  @123904  (61440)   [30 tiles][8 chunks][64 lanes] x 16B bf16-hi
//   Bpl  @185344  (61440)   same, bf16-lo
//   keys @246784  (262144 ints)
//   partials @508928 (32768)

__device__ __forceinline__ void bsplit(float v, short& h, short& lo) {
  unsigned u = __float_as_uint(v);
  unsigned hb = (u + 0x7fffu + ((u >> 16) & 1u)) >> 16;   // RNE to bf16
  float hf = __uint_as_float(hb << 16);
  float lf = v - hf;
  unsigned u2 = __float_as_uint(lf);
  unsigned lb = (u2 + 0x7fffu + ((u2 >> 16) & 1u)) >> 16;
  h = (short)hb; lo = (short)lb;
}

// ---- kernel 0: column norms + transposed fp32 dict copies (exact, for gather) ----
__global__ void vq_prep(const float* __restrict__ D0, const float* __restrict__ D1,
                        const float* __restrict__ D2, const float* __restrict__ D3,
                        float* __restrict__ nrm, float* __restrict__ DT) {
  int g = blockIdx.x * 256 + threadIdx.x;
  if (g >= 960) return;
  const float* D; int K, k; float* T;
  if (g < 64)       { D = D0; K = 64;  k = g;       T = DT; }
  else if (g < 192) { D = D1; K = 128; k = g - 64;  T = DT + 8192; }
  else if (g < 448) { D = D2; K = 256; k = g - 192; T = DT + 24576; }
  else              { D = D3; K = 512; k = g - 448; T = DT + 57344; }
  float s = 0.f;
  for (int c = 0; c < 128; ++c) { float v = D[c*K+k]; s = fmaf(v,v,s); T[k*128+c] = v; }
  nrm[g] = s;
}

// ---- kernel 1: pack dicts into MFMA B-fragment order, bf16 hi/lo ----
// entry g = (T*8 + c)*64 + lane: 8 bf16 = B[k0+j][col], col = T*32+(l&31), k0 = 16c+8*(l>>5)
__global__ void vq_pack(const float* __restrict__ D0, const float* __restrict__ D1,
                        const float* __restrict__ D2, const float* __restrict__ D3,
                        bf8v* __restrict__ Bph, bf8v* __restrict__ Bpl) {
  int g = blockIdx.x * 256 + threadIdx.x;           // 60*256 = 15360 exact
  int T = g >> 9, c = (g >> 6) & 7, l = g & 63;
  int col = T * 32 + (l & 31);
  int k0 = c * 16 + (l >> 5) * 8;
  const float* D; int K, cb;
  if (col < 64)       { D = D0; K = 64;  cb = col; }
  else if (col < 192) { D = D1; K = 128; cb = col - 64; }
  else if (col < 448) { D = D2; K = 256; cb = col - 192; }
  else                { D = D3; K = 512; cb = col - 448; }
  short h0,h1,h2,h3,h4,h5,h6,h7, q0,q1,q2,q3,q4,q5,q6,q7;
  bsplit(D[(k0+0)*K + cb], h0, q0);
  bsplit(D[(k0+1)*K + cb], h1, q1);
  bsplit(D[(k0+2)*K + cb], h2, q2);
  bsplit(D[(k0+3)*K + cb], h3, q3);
  bsplit(D[(k0+4)*K + cb], h4, q4);
  bsplit(D[(k0+5)*K + cb], h5, q5);
  bsplit(D[(k0+6)*K + cb], h6, q6);
  bsplit(D[(k0+7)*K + cb], h7, q7);
  Bph[g] = (bf8v){h0,h1,h2,h3,h4,h5,h6,h7};
  Bpl[g] = (bf8v){q0,q1,q2,q3,q4,q5,q6,q7};
}

#define MK8(U0, U1, HD, LD) { \
  short h0,h1,h2,h3,h4,h5,h6,h7, q0,q1,q2,q3,q4,q5,q6,q7; \
  bsplit(U0.x,h0,q0); bsplit(U0.y,h1,q1); bsplit(U0.z,h2,q2); bsplit(U0.w,h3,q3); \
  bsplit(U1.x,h4,q4); bsplit(U1.y,h5,q5); bsplit(U1.z,h6,q6); bsplit(U1.w,h7,q7); \
  HD = (bf8v){h0,h1,h2,h3,h4,h5,h6,h7}; \
  LD = (bf8v){q0,q1,q2,q3,q4,q5,q6,q7}; }

#define MFMA32(AC, AF, BF) AC = __builtin_amdgcn_mfma_f32_32x32x16_bf16((AF), (BF), (AC), 0, 0, 0)

// one 32-col tile: 16 coalesced B loads + 24 MFMAs + criterion (no LDS, no barriers)
#define TILE2(T) { \
  const bf8v* __restrict__ BhT = Bph + (T) * 512 + l; \
  const bf8v* __restrict__ BlT = Bpl + (T) * 512 + l; \
  f32x16 ae = zero16, ao = zero16; \
  _Pragma("unroll") \
  for (int cp = 0; cp < 4; ++cp) { \
    const int ce = 2*cp, co = 2*cp+1; \
    bf8v bhe = BhT[ce*64]; bf8v bho = BhT[co*64]; \
    bf8v ble = BlT[ce*64]; bf8v blo = BlT[co*64]; \
    MFMA32(ae, Ah[ce], bhe); MFMA32(ao, Ah[co], bho); \
    MFMA32(ae, Al[ce], bhe); MFMA32(ao, Al[co], bho); \
    MFMA32(ae, Ah[ce], ble); MFMA32(ao, Ah[co], blo); \
  } \
  f32x16 sv = ae + ao; \
  const float nv = nrm_g[(T)*32 + (l & 31)]; \
  const int colT = (T)*32 + (l & 31); \
  _Pragma("unroll") \
  for (int r = 0; r < 16; ++r) { \
    float c0 = fmaf(-2.f, sv[r], nv); \
    if (c0 < bc[r]) { bc[r] = c0; bk[r] = colT; } } }

// lex-min argmin flush for one dict segment; reset running best
#define FLUSH1(DICTID, BASE) { \
  _Pragma("unroll") \
  for (int r = 0; r < 16; ++r) { \
    float b0 = bc[r]; int K0 = bk[r]; \
    _Pragma("unroll") \
    for (int m = 1; m <= 16; m <<= 1) { \
      float pb = __shfl_xor(b0, m); int pk = __shfl_xor(K0, m); \
      if (pb < b0 || (pb == b0 && pk < K0)) { b0 = pb; K0 = pk; } } \
    if ((l & 31) == 0) { \
      const int ro = (r & 3) + 8 * (r >> 2) + 4 * hl; \
      keys[((rowbase + ro) << 2) | (DICTID)] = K0 - (BASE); } \
    bc[r] = 1e30f; bk[r] = 0; } }

// ---- kernel 2: MFMA scoring. 4096 single-wave blocks: (row tile) x (dict part) ----
// part 0: dicts 0/1/2 (tiles 0..13); part 1: dict 3 (tiles 14..29). Disjoint key slots.
__global__ __launch_bounds__(64, 4) void vq_mfma(
    const float* __restrict__ x,
    const bf8v* __restrict__ Bph, const bf8v* __restrict__ Bpl,
    const float* __restrict__ nrm_g, int* __restrict__ keys)
{
  const int l = threadIdx.x;
  const int hl = l >> 5;
  const int b = blockIdx.x;
  const int rowbase = (b >> 1) * 32;
  const int part = b & 1;

  // A fragments straight from global: row = rowbase + (l&31), k0 = 16c + 8*hl
  bf8v Ah[8], Al[8];
  {
    const float* __restrict__ xr = x + (size_t)(rowbase + (l & 31)) * CDIM + hl * 8;
    #pragma unroll
    for (int c = 0; c < 8; ++c) {
      float4 u0 = *(const float4*)(xr + c * 16);
      float4 u1 = *(const float4*)(xr + c * 16 + 4);
      MK8(u0, u1, Ah[c], Al[c])
    }
  }

  f32x16 zero16;
  #pragma unroll
  for (int i = 0; i < 16; ++i) zero16[i] = 0.f;

  float bc[16]; int bk[16];
  #pragma unroll
  for (int r = 0; r < 16; ++r) { bc[r] = 1e30f; bk[r] = 0; }

  if (part == 0) {
    // dict boundaries at tiles {2,6,14}
    for (int T = 0; T < 2; ++T) TILE2(T)
    FLUSH1(0, 0)
    #pragma unroll 2
    for (int T = 2; T < 6; ++T) TILE2(T)
    FLUSH1(1, 64)
    #pragma unroll 2
    for (int T = 6; T < 14; ++T) TILE2(T)
    FLUSH1(2, 192)
  } else {
    #pragma unroll 2
    for (int T = 14; T < 30; ++T) TILE2(T)
    FLUSH1(3, 448)
  }
}

// ---- kernel 3: gather winners (coalesced via DT), write out + loss partials ----
__global__ __launch_bounds__(256, 8) void vq_merge(
    const float* __restrict__ x, const float* __restrict__ DT,
    const int* __restrict__ keys,
    const float* __restrict__ alpha_p, const float* __restrict__ gamma_p,
    float* __restrict__ out, float* __restrict__ partials)
{
  __shared__ int kk[2][4];
  __shared__ float wr[4];
  const int t = threadIdx.x;
  const int c = t & 127, rs = t >> 7;
  const int row0 = blockIdx.x * 2;
  if (t < 8) {
    int r = t >> 2, d = t & 3;
    kk[r][d] = keys[((row0 + r) << 2) | d];
  }
  __syncthreads();
  const int row = row0 + rs;
  const float a = alpha_p[0];
  const float g0 = gamma_p[0], g1 = gamma_p[1], g2 = gamma_p[2], g3 = gamma_p[3];
  const float xv = x[(size_t)row * CDIM + c];
  const float d0 = DT[         kk[rs][0] * 128 + c];
  const float d1 = DT[ 8192  + kk[rs][1] * 128 + c];
  const float d2 = DT[ 24576 + kk[rs][2] * 128 + c];
  const float d3 = DT[ 57344 + kk[rs][3] * 128 + c];
  out[(size_t)row * CDIM + c] = a * (g0*d0 + g1*d1 + g2*d2 + g3*d3);
  float e0 = fmaf(-a, d0, xv), e1 = fmaf(-a, d1, xv);
  float e2 = fmaf(-a, d2, xv), e3 = fmaf(-a, d3, xv);
  float lc = g0*e0*e0 + g1*e1*e1 + g2*e2*e2 + g3*e3*e3;
  #pragma unroll
  for (int off = 32; off > 0; off >>= 1) lc += __shfl_down(lc, off);
  if ((t & 63) == 0) wr[t >> 6] = lc;
  __syncthreads();
  if (t == 0) partials[blockIdx.x] = wr[0] + wr[1] + wr[2] + wr[3];
}

// ---- kernel 4: final deterministic loss reduction ----
__global__ void vq_loss(const float* __restrict__ partials, float* __restrict__ lossp) {
  __shared__ float wr[4];
  const int t = threadIdx.x;
  float v = 0.f;
  #pragma unroll 8
  for (int i = 0; i < 128; ++i) v += partials[i * 256 + t];
  #pragma unroll
  for (int off = 32; off > 0; off >>= 1) v += __shfl_down(v, off);
  if ((t & 63) == 0) wr[t >> 6] = v;
  __syncthreads();
  if (t == 0) lossp[0] = (wr[0] + wr[1] + wr[2] + wr[3]) * (1.25f / 8388608.f);
}

extern "C" void kernel_launch(void* const* d_in, const int* in_sizes, int n_in,
                              void* d_out, int out_size, void* d_ws, size_t ws_size,
                              hipStream_t stream) {
  const float* x  = (const float*)d_in[0];
  const float* D0 = (const float*)d_in[1];
  const float* D1 = (const float*)d_in[2];
  const float* D2 = (const float*)d_in[3];
  const float* D3 = (const float*)d_in[4];
  const float* alpha = (const float*)d_in[5];
  const float* gamma = (const float*)d_in[6];
  float* out = (float*)d_out;

  float* ws  = (float*)d_ws;
  float* nrm = ws;                         // 1024
  float* DT  = ws + 1024;                  // 122880
  bf8v*  Bph = (bf8v*)(ws + 123904);       // 61440 floats
  bf8v*  Bpl = (bf8v*)(ws + 185344);       // 61440 floats
  int*  keys = (int*)(ws + 246784);        // 262144 ints
  float* partials = ws + 508928;           // 32768

  vq_prep<<<4, 256, 0, stream>>>(D0, D1, D2, D3, nrm, DT);
  vq_pack<<<60, 256, 0, stream>>>(D0, D1, D2, D3, Bph, Bpl);
  vq_mfma<<<4096, 64, 0, stream>>>(x, Bph, Bpl, nrm, keys);
  vq_merge<<<32768, 256, 0, stream>>>(x, DT, keys, alpha, gamma, out, partials);
  vq_loss<<<1, 256, 0, stream>>>(partials, out + NC);
}

// Round 13
// 157.821 us; speedup vs baseline: 1.3571x; 1.3571x over previous
//
#include <hip/hip_runtime.h>

#define CDIM 128
#define NC   8388608

typedef __attribute__((ext_vector_type(8)))  short bf8v;   // 8 bf16 (4 VGPRs)
typedef __attribute__((ext_vector_type(16))) float f32x16; // MFMA 32x32 acc

// ws layout (float offsets):
//   nrm  @0       (1024)
//   DT   @1024    (122880)
//   Bph  @123904  (61440)   [30 tiles][8 chunks][64 lanes] x 16B bf16-hi
//   Bpl  @185344  (61440)   same, bf16-lo
//   keys @246784  (262144 ints)
//   partials @508928 (32768)

__device__ __forceinline__ void bsplit(float v, short& h, short& lo) {
  unsigned u = __float_as_uint(v);
  unsigned hb = (u + 0x7fffu + ((u >> 16) & 1u)) >> 16;   // RNE to bf16
  float hf = __uint_as_float(hb << 16);
  float lf = v - hf;
  unsigned u2 = __float_as_uint(lf);
  unsigned lb = (u2 + 0x7fffu + ((u2 >> 16) & 1u)) >> 16;
  h = (short)hb; lo = (short)lb;
}

// ---- kernel 0: column norms + transposed fp32 dict copies (exact, for gather) ----
__global__ void vq_prep(const float* __restrict__ D0, const float* __restrict__ D1,
                        const float* __restrict__ D2, const float* __restrict__ D3,
                        float* __restrict__ nrm, float* __restrict__ DT) {
  int g = blockIdx.x * 256 + threadIdx.x;
  if (g >= 960) return;
  const float* D; int K, k; float* T;
  if (g < 64)       { D = D0; K = 64;  k = g;       T = DT; }
  else if (g < 192) { D = D1; K = 128; k = g - 64;  T = DT + 8192; }
  else if (g < 448) { D = D2; K = 256; k = g - 192; T = DT + 24576; }
  else              { D = D3; K = 512; k = g - 448; T = DT + 57344; }
  float s = 0.f;
  for (int c = 0; c < 128; ++c) { float v = D[c*K+k]; s = fmaf(v,v,s); T[k*128+c] = v; }
  nrm[g] = s;
}

// ---- kernel 1: pack dicts into MFMA B-fragment order, bf16 hi/lo ----
// entry g = (T*8 + c)*64 + lane: 8 bf16 = B[k0+j][col], col = T*32+(l&31), k0 = 16c+8*(l>>5)
__global__ void vq_pack(const float* __restrict__ D0, const float* __restrict__ D1,
                        const float* __restrict__ D2, const float* __restrict__ D3,
                        bf8v* __restrict__ Bph, bf8v* __restrict__ Bpl) {
  int g = blockIdx.x * 256 + threadIdx.x;           // 60*256 = 15360 exact
  int T = g >> 9, c = (g >> 6) & 7, l = g & 63;
  int col = T * 32 + (l & 31);
  int k0 = c * 16 + (l >> 5) * 8;
  const float* D; int K, cb;
  if (col < 64)       { D = D0; K = 64;  cb = col; }
  else if (col < 192) { D = D1; K = 128; cb = col - 64; }
  else if (col < 448) { D = D2; K = 256; cb = col - 192; }
  else                { D = D3; K = 512; cb = col - 448; }
  short h0,h1,h2,h3,h4,h5,h6,h7, q0,q1,q2,q3,q4,q5,q6,q7;
  bsplit(D[(k0+0)*K + cb], h0, q0);
  bsplit(D[(k0+1)*K + cb], h1, q1);
  bsplit(D[(k0+2)*K + cb], h2, q2);
  bsplit(D[(k0+3)*K + cb], h3, q3);
  bsplit(D[(k0+4)*K + cb], h4, q4);
  bsplit(D[(k0+5)*K + cb], h5, q5);
  bsplit(D[(k0+6)*K + cb], h6, q6);
  bsplit(D[(k0+7)*K + cb], h7, q7);
  Bph[g] = (bf8v){h0,h1,h2,h3,h4,h5,h6,h7};
  Bpl[g] = (bf8v){q0,q1,q2,q3,q4,q5,q6,q7};
}

#define MK8(U0, U1, HD, LD) { \
  short h0,h1,h2,h3,h4,h5,h6,h7, q0,q1,q2,q3,q4,q5,q6,q7; \
  bsplit(U0.x,h0,q0); bsplit(U0.y,h1,q1); bsplit(U0.z,h2,q2); bsplit(U0.w,h3,q3); \
  bsplit(U1.x,h4,q4); bsplit(U1.y,h5,q5); bsplit(U1.z,h6,q6); bsplit(U1.w,h7,q7); \
  HD = (bf8v){h0,h1,h2,h3,h4,h5,h6,h7}; \
  LD = (bf8v){q0,q1,q2,q3,q4,q5,q6,q7}; }

#define MFMA32(AC, AF, BF) AC = __builtin_amdgcn_mfma_f32_32x32x16_bf16((AF), (BF), (AC), 0, 0, 0)

// one 32-col tile: 16 coalesced B loads + 24 MFMAs + criterion (no LDS, no barriers)
#define TILE2(T) { \
  const bf8v* __restrict__ BhT = Bph + (T) * 512 + l; \
  const bf8v* __restrict__ BlT = Bpl + (T) * 512 + l; \
  f32x16 ae = zero16, ao = zero16; \
  _Pragma("unroll") \
  for (int cp = 0; cp < 4; ++cp) { \
    const int ce = 2*cp, co = 2*cp+1; \
    bf8v bhe = BhT[ce*64]; bf8v bho = BhT[co*64]; \
    bf8v ble = BlT[ce*64]; bf8v blo = BlT[co*64]; \
    MFMA32(ae, Ah[ce], bhe); MFMA32(ao, Ah[co], bho); \
    MFMA32(ae, Al[ce], bhe); MFMA32(ao, Al[co], bho); \
    MFMA32(ae, Ah[ce], ble); MFMA32(ao, Ah[co], blo); \
  } \
  f32x16 sv = ae + ao; \
  const float nv = nrm_g[(T)*32 + (l & 31)]; \
  const int colT = (T)*32 + (l & 31); \
  _Pragma("unroll") \
  for (int r = 0; r < 16; ++r) { \
    float c0 = fmaf(-2.f, sv[r], nv); \
    if (c0 < bc[r]) { bc[r] = c0; bk[r] = colT; } } }

// lex-min argmin flush for one dict segment; reset running best
#define FLUSH1(DICTID, BASE) { \
  _Pragma("unroll") \
  for (int r = 0; r < 16; ++r) { \
    float b0 = bc[r]; int K0 = bk[r]; \
    _Pragma("unroll") \
    for (int m = 1; m <= 16; m <<= 1) { \
      float pb = __shfl_xor(b0, m); int pk = __shfl_xor(K0, m); \
      if (pb < b0 || (pb == b0 && pk < K0)) { b0 = pb; K0 = pk; } } \
    if ((l & 31) == 0) { \
      const int ro = (r & 3) + 8 * (r >> 2) + 4 * hl; \
      keys[((rowbase + ro) << 2) | (DICTID)] = K0 - (BASE); } \
    bc[r] = 1e30f; bk[r] = 0; } }

// ---- kernel 2: MFMA scoring. 4096 single-wave blocks: (row tile) x (dict part) ----
// part 0: dicts 0/1/2 (tiles 0..13); part 1: dict 3 (tiles 14..29). Disjoint key slots.
// launch_bounds(64,2): known-good codegen (r11: 120 VGPR, no spill); 120<=128 still
// lets HW run 4 waves/SIMD, and the 4096-block grid now supplies them.
__global__ __launch_bounds__(64, 2) void vq_mfma(
    const float* __restrict__ x,
    const bf8v* __restrict__ Bph, const bf8v* __restrict__ Bpl,
    const float* __restrict__ nrm_g, int* __restrict__ keys)
{
  const int l = threadIdx.x;
  const int hl = l >> 5;
  const int b = blockIdx.x;
  const int rowbase = (b >> 1) * 32;
  const int part = b & 1;

  // A fragments straight from global: row = rowbase + (l&31), k0 = 16c + 8*hl
  bf8v Ah[8], Al[8];
  {
    const float* __restrict__ xr = x + (size_t)(rowbase + (l & 31)) * CDIM + hl * 8;
    #pragma unroll
    for (int c = 0; c < 8; ++c) {
      float4 u0 = *(const float4*)(xr + c * 16);
      float4 u1 = *(const float4*)(xr + c * 16 + 4);
      MK8(u0, u1, Ah[c], Al[c])
    }
  }

  f32x16 zero16;
  #pragma unroll
  for (int i = 0; i < 16; ++i) zero16[i] = 0.f;

  float bc[16]; int bk[16];
  #pragma unroll
  for (int r = 0; r < 16; ++r) { bc[r] = 1e30f; bk[r] = 0; }

  if (part == 0) {
    // dict boundaries at tiles {2,6,14}
    for (int T = 0; T < 2; ++T) TILE2(T)
    FLUSH1(0, 0)
    #pragma unroll 2
    for (int T = 2; T < 6; ++T) TILE2(T)
    FLUSH1(1, 64)
    #pragma unroll 2
    for (int T = 6; T < 14; ++T) TILE2(T)
    FLUSH1(2, 192)
  } else {
    #pragma unroll 2
    for (int T = 14; T < 30; ++T) TILE2(T)
    FLUSH1(3, 448)
  }
}

// ---- kernel 3: gather winners (coalesced via DT), write out + loss partials ----
__global__ __launch_bounds__(256, 8) void vq_merge(
    const float* __restrict__ x, const float* __restrict__ DT,
    const int* __restrict__ keys,
    const float* __restrict__ alpha_p, const float* __restrict__ gamma_p,
    float* __restrict__ out, float* __restrict__ partials)
{
  __shared__ int kk[2][4];
  __shared__ float wr[4];
  const int t = threadIdx.x;
  const int c = t & 127, rs = t >> 7;
  const int row0 = blockIdx.x * 2;
  if (t < 8) {
    int r = t >> 2, d = t & 3;
    kk[r][d] = keys[((row0 + r) << 2) | d];
  }
  __syncthreads();
  const int row = row0 + rs;
  const float a = alpha_p[0];
  const float g0 = gamma_p[0], g1 = gamma_p[1], g2 = gamma_p[2], g3 = gamma_p[3];
  const float xv = x[(size_t)row * CDIM + c];
  const float d0 = DT[         kk[rs][0] * 128 + c];
  const float d1 = DT[ 8192  + kk[rs][1] * 128 + c];
  const float d2 = DT[ 24576 + kk[rs][2] * 128 + c];
  const float d3 = DT[ 57344 + kk[rs][3] * 128 + c];
  out[(size_t)row * CDIM + c] = a * (g0*d0 + g1*d1 + g2*d2 + g3*d3);
  float e0 = fmaf(-a, d0, xv), e1 = fmaf(-a, d1, xv);
  float e2 = fmaf(-a, d2, xv), e3 = fmaf(-a, d3, xv);
  float lc = g0*e0*e0 + g1*e1*e1 + g2*e2*e2 + g3*e3*e3;
  #pragma unroll
  for (int off = 32; off > 0; off >>= 1) lc += __shfl_down(lc, off);
  if ((t & 63) == 0) wr[t >> 6] = lc;
  __syncthreads();
  if (t == 0) partials[blockIdx.x] = wr[0] + wr[1] + wr[2] + wr[3];
}

// ---- kernel 4: final deterministic loss reduction ----
__global__ void vq_loss(const float* __restrict__ partials, float* __restrict__ lossp) {
  __shared__ float wr[4];
  const int t = threadIdx.x;
  float v = 0.f;
  #pragma unroll 8
  for (int i = 0; i < 128; ++i) v += partials[i * 256 + t];
  #pragma unroll
  for (int off = 32; off > 0; off >>= 1) v += __shfl_down(v, off);
  if ((t & 63) == 0) wr[t >> 6] = v;
  __syncthreads();
  if (t == 0) lossp[0] = (wr[0] + wr[1] + wr[2] + wr[3]) * (1.25f / 8388608.f);
}

extern "C" void kernel_launch(void* const* d_in, const int* in_sizes, int n_in,
                              void* d_out, int out_size, void* d_ws, size_t ws_size,
                              hipStream_t stream) {
  const float* x  = (const float*)d_in[0];
  const float* D0 = (const float*)d_in[1];
  const float* D1 = (const float*)d_in[2];
  const float* D2 = (const float*)d_in[3];
  const float* D3 = (const float*)d_in[4];
  const float* alpha = (const float*)d_in[5];
  const float* gamma = (const float*)d_in[6];
  float* out = (float*)d_out;

  float* ws  = (float*)d_ws;
  float* nrm = ws;                         // 1024
  float* DT  = ws + 1024;                  // 122880
  bf8v*  Bph = (bf8v*)(ws + 123904);       // 61440 floats
  bf8v*  Bpl = (bf8v*)(ws + 185344);       // 61440 floats
  int*  keys = (int*)(ws + 246784);        // 262144 ints
  float* partials = ws + 508928;           // 32768

  vq_prep<<<4, 256, 0, stream>>>(D0, D1, D2, D3, nrm, DT);
  vq_pack<<<60, 256, 0, stream>>>(D0, D1, D2, D3, Bph, Bpl);
  vq_mfma<<<4096, 64, 0, stream>>>(x, Bph, Bpl, nrm, keys);
  vq_merge<<<32768, 256, 0, stream>>>(x, DT, keys, alpha, gamma, out, partials);
  vq_loss<<<1, 256, 0, stream>>>(partials, out + NC);
}

// Round 14
// 126.663 us; speedup vs baseline: 1.6909x; 1.2460x over previous
//
#include <hip/hip_runtime.h>

#define CDIM 128
#define NC   8388608

typedef __attribute__((ext_vector_type(8)))  short bf8v;   // 8 bf16 (4 VGPRs)
typedef __attribute__((ext_vector_type(16))) float f32x16; // MFMA 32x32 acc

// ws layout (float offsets):
//   nrm  @0       (1024)
//   DT   @1024    (122880)
//   Bph  @123904  (61440)   [30 tiles][8 chunks][64 lanes] x 16B bf16-hi
//   Bpl  @185344  (61440)   same, bf16-lo
//   keys @246784  (262144 ints)
//   partials @508928 (32768)

__device__ __forceinline__ void bsplit(float v, short& h, short& lo) {
  unsigned u = __float_as_uint(v);
  unsigned hb = (u + 0x7fffu + ((u >> 16) & 1u)) >> 16;   // RNE to bf16
  float hf = __uint_as_float(hb << 16);
  float lf = v - hf;
  unsigned u2 = __float_as_uint(lf);
  unsigned lb = (u2 + 0x7fffu + ((u2 >> 16) & 1u)) >> 16;
  h = (short)hb; lo = (short)lb;
}

// ---- kernel 0: column norms + transposed fp32 dict copies (exact, for gather) ----
__global__ void vq_prep(const float* __restrict__ D0, const float* __restrict__ D1,
                        const float* __restrict__ D2, const float* __restrict__ D3,
                        float* __restrict__ nrm, float* __restrict__ DT) {
  int g = blockIdx.x * 256 + threadIdx.x;
  if (g >= 960) return;
  const float* D; int K, k; float* T;
  if (g < 64)       { D = D0; K = 64;  k = g;       T = DT; }
  else if (g < 192) { D = D1; K = 128; k = g - 64;  T = DT + 8192; }
  else if (g < 448) { D = D2; K = 256; k = g - 192; T = DT + 24576; }
  else              { D = D3; K = 512; k = g - 448; T = DT + 57344; }
  float s = 0.f;
  for (int c = 0; c < 128; ++c) { float v = D[c*K+k]; s = fmaf(v,v,s); T[k*128+c] = v; }
  nrm[g] = s;
}

// ---- kernel 1: pack dicts into MFMA B-fragment order, bf16 hi/lo ----
// entry g = (T*8 + c)*64 + lane: 8 bf16 = B[k0+j][col], col = T*32+(l&31), k0 = 16c+8*(l>>5)
__global__ void vq_pack(const float* __restrict__ D0, const float* __restrict__ D1,
                        const float* __restrict__ D2, const float* __restrict__ D3,
                        bf8v* __restrict__ Bph, bf8v* __restrict__ Bpl) {
  int g = blockIdx.x * 256 + threadIdx.x;           // 60*256 = 15360 exact
  int T = g >> 9, c = (g >> 6) & 7, l = g & 63;
  int col = T * 32 + (l & 31);
  int k0 = c * 16 + (l >> 5) * 8;
  const float* D; int K, cb;
  if (col < 64)       { D = D0; K = 64;  cb = col; }
  else if (col < 192) { D = D1; K = 128; cb = col - 64; }
  else if (col < 448) { D = D2; K = 256; cb = col - 192; }
  else                { D = D3; K = 512; cb = col - 448; }
  short h0,h1,h2,h3,h4,h5,h6,h7, q0,q1,q2,q3,q4,q5,q6,q7;
  bsplit(D[(k0+0)*K + cb], h0, q0);
  bsplit(D[(k0+1)*K + cb], h1, q1);
  bsplit(D[(k0+2)*K + cb], h2, q2);
  bsplit(D[(k0+3)*K + cb], h3, q3);
  bsplit(D[(k0+4)*K + cb], h4, q4);
  bsplit(D[(k0+5)*K + cb], h5, q5);
  bsplit(D[(k0+6)*K + cb], h6, q6);
  bsplit(D[(k0+7)*K + cb], h7, q7);
  Bph[g] = (bf8v){h0,h1,h2,h3,h4,h5,h6,h7};
  Bpl[g] = (bf8v){q0,q1,q2,q3,q4,q5,q6,q7};
}

#define MK8(U0, U1, HD, LD) { \
  short h0,h1,h2,h3,h4,h5,h6,h7, q0,q1,q2,q3,q4,q5,q6,q7; \
  bsplit(U0.x,h0,q0); bsplit(U0.y,h1,q1); bsplit(U0.z,h2,q2); bsplit(U0.w,h3,q3); \
  bsplit(U1.x,h4,q4); bsplit(U1.y,h5,q5); bsplit(U1.z,h6,q6); bsplit(U1.w,h7,q7); \
  HD = (bf8v){h0,h1,h2,h3,h4,h5,h6,h7}; \
  LD = (bf8v){q0,q1,q2,q3,q4,q5,q6,q7}; }

#define MFMA32(AC, AF, BF) AC = __builtin_amdgcn_mfma_f32_32x32x16_bf16((AF), (BF), (AC), 0, 0, 0)

// prefetch tile TT's packed B (16 KB) into 4 named regs per thread (coalesced 16B)
#define PF_T(TT) { \
  const bf8v* __restrict__ gh = Bph + (TT) * 512; \
  const bf8v* __restrict__ gl = Bpl + (TT) * 512; \
  pf0 = gh[t]; pf1 = gh[256 + t]; pf2 = gl[t]; pf3 = gl[256 + t]; }

// write prefetched tile to LDS: contiguous 16B per thread -> conflict-free b128
#define STORE_T() { \
  BL[t] = pf0; BL[256 + t] = pf1; BL[512 + t] = pf2; BL[768 + t] = pf3; }

// one 32-col tile from LDS: 16 ds_read_b128 + 24 MFMAs + criterion
#define COMPUTE_T(T) { \
  f32x16 ae = zero16, ao = zero16; \
  _Pragma("unroll") \
  for (int cp = 0; cp < 4; ++cp) { \
    const int ce = 2*cp, co = 2*cp+1; \
    bf8v bhe = BL[ce*64 + l]; bf8v bho = BL[co*64 + l]; \
    bf8v ble = BL[512 + ce*64 + l]; bf8v blo = BL[512 + co*64 + l]; \
    MFMA32(ae, Ah[ce], bhe); MFMA32(ao, Ah[co], bho); \
    MFMA32(ae, Al[ce], bhe); MFMA32(ao, Al[co], bho); \
    MFMA32(ae, Ah[ce], ble); MFMA32(ao, Ah[co], blo); \
  } \
  f32x16 sv = ae + ao; \
  const float nv = nrm_g[(T)*32 + (l & 31)]; \
  const int colT = (T)*32 + (l & 31); \
  _Pragma("unroll") \
  for (int r = 0; r < 16; ++r) { \
    float c0 = fmaf(-2.f, sv[r], nv); \
    if (c0 < bc[r]) { bc[r] = c0; bk[r] = colT; } } }

// pipeline round: drain readers -> store staged tile -> issue next prefetch -> compute
#define ROUND_T(T, TN) { \
  __syncthreads(); \
  STORE_T(); \
  __syncthreads(); \
  PF_T(TN); \
  COMPUTE_T(T) }

// lex-min argmin flush for one dict segment; reset running best
#define FLUSH1(DICTID, BASE) { \
  _Pragma("unroll") \
  for (int r = 0; r < 16; ++r) { \
    float b0 = bc[r]; int K0 = bk[r]; \
    _Pragma("unroll") \
    for (int m = 1; m <= 16; m <<= 1) { \
      float pb = __shfl_xor(b0, m); int pk = __shfl_xor(K0, m); \
      if (pb < b0 || (pb == b0 && pk < K0)) { b0 = pb; K0 = pk; } } \
    if ((l & 31) == 0) { \
      const int ro = (r & 3) + 8 * (r >> 2) + 4 * hl; \
      keys[((rowbase + ro) << 2) | (DICTID)] = K0 - (BASE); } \
    bc[r] = 1e30f; bk[r] = 0; } }

// ---- kernel 2: MFMA scoring. 1024 blocks x 256 thr: 4 waves share LDS B tile ----
// block b: rows (b>>1)*128 .. +127 (wave w owns 32); part b&1: 0 = dicts 0/1/2, 1 = dict 3.
__global__ __launch_bounds__(256, 3) void vq_mfma(
    const float* __restrict__ x,
    const bf8v* __restrict__ Bph, const bf8v* __restrict__ Bpl,
    const float* __restrict__ nrm_g, int* __restrict__ keys)
{
  __shared__ bf8v BL[1024];   // 16 KB: [0..511] Bh tile, [512..1023] Bl tile

  const int t = threadIdx.x;
  const int w = t >> 6, l = t & 63;
  const int hl = l >> 5;
  const int b = blockIdx.x;
  const int rowbase = (b >> 1) * 128 + w * 32;
  const int part = b & 1;

  // A fragments straight from global: row = rowbase + (l&31), k0 = 16c + 8*hl
  bf8v Ah[8], Al[8];
  {
    const float* __restrict__ xr = x + (size_t)(rowbase + (l & 31)) * CDIM + hl * 8;
    #pragma unroll
    for (int c = 0; c < 8; ++c) {
      float4 u0 = *(const float4*)(xr + c * 16);
      float4 u1 = *(const float4*)(xr + c * 16 + 4);
      MK8(u0, u1, Ah[c], Al[c])
    }
  }

  f32x16 zero16;
  #pragma unroll
  for (int i = 0; i < 16; ++i) zero16[i] = 0.f;

  float bc[16]; int bk[16];
  #pragma unroll
  for (int r = 0; r < 16; ++r) { bc[r] = 1e30f; bk[r] = 0; }

  bf8v pf0, pf1, pf2, pf3;

  if (part == 0) {
    PF_T(0)
    // dict boundaries at tiles {2,6,14}
    ROUND_T(0, 1)
    ROUND_T(1, 2)
    FLUSH1(0, 0)
    for (int T = 2; T < 6; ++T) ROUND_T(T, T + 1)
    FLUSH1(1, 64)
    for (int T = 6; T < 14; ++T) ROUND_T(T, (T == 13) ? 13 : T + 1)
    FLUSH1(2, 192)
  } else {
    PF_T(14)
    for (int T = 14; T < 30; ++T) ROUND_T(T, (T == 29) ? 29 : T + 1)
    FLUSH1(3, 448)
  }
}

// ---- kernel 3: gather winners (coalesced via DT), write out + loss partials ----
__global__ __launch_bounds__(256, 8) void vq_merge(
    const float* __restrict__ x, const float* __restrict__ DT,
    const int* __restrict__ keys,
    const float* __restrict__ alpha_p, const float* __restrict__ gamma_p,
    float* __restrict__ out, float* __restrict__ partials)
{
  __shared__ int kk[2][4];
  __shared__ float wr[4];
  const int t = threadIdx.x;
  const int c = t & 127, rs = t >> 7;
  const int row0 = blockIdx.x * 2;
  if (t < 8) {
    int r = t >> 2, d = t & 3;
    kk[r][d] = keys[((row0 + r) << 2) | d];
  }
  __syncthreads();
  const int row = row0 + rs;
  const float a = alpha_p[0];
  const float g0 = gamma_p[0], g1 = gamma_p[1], g2 = gamma_p[2], g3 = gamma_p[3];
  const float xv = x[(size_t)row * CDIM + c];
  const float d0 = DT[         kk[rs][0] * 128 + c];
  const float d1 = DT[ 8192  + kk[rs][1] * 128 + c];
  const float d2 = DT[ 24576 + kk[rs][2] * 128 + c];
  const float d3 = DT[ 57344 + kk[rs][3] * 128 + c];
  out[(size_t)row * CDIM + c] = a * (g0*d0 + g1*d1 + g2*d2 + g3*d3);
  float e0 = fmaf(-a, d0, xv), e1 = fmaf(-a, d1, xv);
  float e2 = fmaf(-a, d2, xv), e3 = fmaf(-a, d3, xv);
  float lc = g0*e0*e0 + g1*e1*e1 + g2*e2*e2 + g3*e3*e3;
  #pragma unroll
  for (int off = 32; off > 0; off >>= 1) lc += __shfl_down(lc, off);
  if ((t & 63) == 0) wr[t >> 6] = lc;
  __syncthreads();
  if (t == 0) partials[blockIdx.x] = wr[0] + wr[1] + wr[2] + wr[3];
}

// ---- kernel 4: final deterministic loss reduction ----
__global__ void vq_loss(const float* __restrict__ partials, float* __restrict__ lossp) {
  __shared__ float wr[4];
  const int t = threadIdx.x;
  float v = 0.f;
  #pragma unroll 8
  for (int i = 0; i < 128; ++i) v += partials[i * 256 + t];
  #pragma unroll
  for (int off = 32; off > 0; off >>= 1) v += __shfl_down(v, off);
  if ((t & 63) == 0) wr[t >> 6] = v;
  __syncthreads();
  if (t == 0) lossp[0] = (wr[0] + wr[1] + wr[2] + wr[3]) * (1.25f / 8388608.f);
}

extern "C" void kernel_launch(void* const* d_in, const int* in_sizes, int n_in,
                              void* d_out, int out_size, void* d_ws, size_t ws_size,
                              hipStream_t stream) {
  const float* x  = (const float*)d_in[0];
  const float* D0 = (const float*)d_in[1];
  const float* D1 = (const float*)d_in[2];
  const float* D2 = (const float*)d_in[3];
  const float* D3 = (const float*)d_in[4];
  const float* alpha = (const float*)d_in[5];
  const float* gamma = (const float*)d_in[6];
  float* out = (float*)d_out;

  float* ws  = (float*)d_ws;
  float* nrm = ws;                         // 1024
  float* DT  = ws + 1024;                  // 122880
  bf8v*  Bph = (bf8v*)(ws + 123904);       // 61440 floats
  bf8v*  Bpl = (bf8v*)(ws + 185344);       // 61440 floats
  int*  keys = (int*)(ws + 246784);        // 262144 ints
  float* partials = ws + 508928;           // 32768

  vq_prep<<<4, 256, 0, stream>>>(D0, D1, D2, D3, nrm, DT);
  vq_pack<<<60, 256, 0, stream>>>(D0, D1, D2, D3, Bph, Bpl);
  vq_mfma<<<1024, 256, 0, stream>>>(x, Bph, Bpl, nrm, keys);
  vq_merge<<<32768, 256, 0, stream>>>(x, DT, keys, alpha, gamma, out, partials);
  vq_loss<<<1, 256, 0, stream>>>(partials, out + NC);
}

// Round 15
// 100.035 us; speedup vs baseline: 2.1410x; 1.2662x over previous
//
#include <hip/hip_runtime.h>

#define CDIM 128
#define NC   8388608

typedef __attribute__((ext_vector_type(8)))  short bf8v;   // 8 bf16 (4 VGPRs)
typedef __attribute__((ext_vector_type(16))) float f32x16; // MFMA 32x32 acc

// ws layout (float offsets):
//   nrm  @0       (1024)
//   DT   @1024    (122880)
//   Bph  @123904  (61440)   [30 tiles][8 chunks][64 lanes] x 16B bf16-hi
//   Bpl  @185344  (61440)   same, bf16-lo
//   keys @246784  (262144 ints)
//   partials @508928 (2048)

__device__ __forceinline__ void bsplit(float v, short& h, short& lo) {
  unsigned u = __float_as_uint(v);
  unsigned hb = (u + 0x7fffu + ((u >> 16) & 1u)) >> 16;   // RNE to bf16
  float hf = __uint_as_float(hb << 16);
  float lf = v - hf;
  unsigned u2 = __float_as_uint(lf);
  unsigned lb = (u2 + 0x7fffu + ((u2 >> 16) & 1u)) >> 16;
  h = (short)hb; lo = (short)lb;
}

// ---- kernel 0: column norms + transposed fp32 dict copies (exact, for gather) ----
__global__ void vq_prep(const float* __restrict__ D0, const float* __restrict__ D1,
                        const float* __restrict__ D2, const float* __restrict__ D3,
                        float* __restrict__ nrm, float* __restrict__ DT) {
  int g = blockIdx.x * 256 + threadIdx.x;
  if (g >= 960) return;
  const float* D; int K, k; float* T;
  if (g < 64)       { D = D0; K = 64;  k = g;       T = DT; }
  else if (g < 192) { D = D1; K = 128; k = g - 64;  T = DT + 8192; }
  else if (g < 448) { D = D2; K = 256; k = g - 192; T = DT + 24576; }
  else              { D = D3; K = 512; k = g - 448; T = DT + 57344; }
  float s = 0.f;
  for (int c = 0; c < 128; ++c) { float v = D[c*K+k]; s = fmaf(v,v,s); T[k*128+c] = v; }
  nrm[g] = s;
}

// ---- kernel 1: pack dicts into MFMA B-fragment order, bf16 hi/lo ----
// entry g = (T*8 + c)*64 + lane: 8 bf16 = B[k0+j][col], col = T*32+(l&31), k0 = 16c+8*(l>>5)
__global__ void vq_pack(const float* __restrict__ D0, const float* __restrict__ D1,
                        const float* __restrict__ D2, const float* __restrict__ D3,
                        bf8v* __restrict__ Bph, bf8v* __restrict__ Bpl) {
  int g = blockIdx.x * 256 + threadIdx.x;           // 60*256 = 15360 exact
  int T = g >> 9, c = (g >> 6) & 7, l = g & 63;
  int col = T * 32 + (l & 31);
  int k0 = c * 16 + (l >> 5) * 8;
  const float* D; int K, cb;
  if (col < 64)       { D = D0; K = 64;  cb = col; }
  else if (col < 192) { D = D1; K = 128; cb = col - 64; }
  else if (col < 448) { D = D2; K = 256; cb = col - 192; }
  else                { D = D3; K = 512; cb = col - 448; }
  short h0,h1,h2,h3,h4,h5,h6,h7, q0,q1,q2,q3,q4,q5,q6,q7;
  bsplit(D[(k0+0)*K + cb], h0, q0);
  bsplit(D[(k0+1)*K + cb], h1, q1);
  bsplit(D[(k0+2)*K + cb], h2, q2);
  bsplit(D[(k0+3)*K + cb], h3, q3);
  bsplit(D[(k0+4)*K + cb], h4, q4);
  bsplit(D[(k0+5)*K + cb], h5, q5);
  bsplit(D[(k0+6)*K + cb], h6, q6);
  bsplit(D[(k0+7)*K + cb], h7, q7);
  Bph[g] = (bf8v){h0,h1,h2,h3,h4,h5,h6,h7};
  Bpl[g] = (bf8v){q0,q1,q2,q3,q4,q5,q6,q7};
}

#define MK8(U0, U1, HD, LD) { \
  short h0,h1,h2,h3,h4,h5,h6,h7, q0,q1,q2,q3,q4,q5,q6,q7; \
  bsplit(U0.x,h0,q0); bsplit(U0.y,h1,q1); bsplit(U0.z,h2,q2); bsplit(U0.w,h3,q3); \
  bsplit(U1.x,h4,q4); bsplit(U1.y,h5,q5); bsplit(U1.z,h6,q6); bsplit(U1.w,h7,q7); \
  HD = (bf8v){h0,h1,h2,h3,h4,h5,h6,h7}; \
  LD = (bf8v){q0,q1,q2,q3,q4,q5,q6,q7}; }

#define MFMA32(AC, AF, BF) AC = __builtin_amdgcn_mfma_f32_32x32x16_bf16((AF), (BF), (AC), 0, 0, 0)

// prefetch tile TT's packed B (16 KB) into 4 named regs per thread (coalesced 16B)
#define PF_T(TT) { \
  const bf8v* __restrict__ gh = Bph + (TT) * 512; \
  const bf8v* __restrict__ gl = Bpl + (TT) * 512; \
  pf0 = gh[t]; pf1 = gh[256 + t]; pf2 = gl[t]; pf3 = gl[256 + t]; }

// write prefetched regs into LDS buffer BF (contiguous 16B/thread -> conflict-free b128)
#define STORE_T(BF) { \
  BL[BF][t] = pf0; BL[BF][256 + t] = pf1; BL[BF][512 + t] = pf2; BL[BF][768 + t] = pf3; }

// one 32-col tile from LDS buffer BF: 16 ds_read_b128 + 24 MFMAs + criterion
#define COMPUTE_T(T, BF) { \
  f32x16 ae = zero16, ao = zero16; \
  _Pragma("unroll") \
  for (int cp = 0; cp < 4; ++cp) { \
    const int ce = 2*cp, co = 2*cp+1; \
    bf8v bhe = BL[BF][ce*64 + l]; bf8v bho = BL[BF][co*64 + l]; \
    bf8v ble = BL[BF][512 + ce*64 + l]; bf8v blo = BL[BF][512 + co*64 + l]; \
    MFMA32(ae, Ah[ce], bhe); MFMA32(ao, Ah[co], bho); \
    MFMA32(ae, Al[ce], bhe); MFMA32(ao, Al[co], bho); \
    MFMA32(ae, Ah[ce], ble); MFMA32(ao, Ah[co], blo); \
  } \
  f32x16 sv = ae + ao; \
  const float nv = nrm_g[(T)*32 + (l & 31)]; \
  const int colT = (T)*32 + (l & 31); \
  _Pragma("unroll") \
  for (int r = 0; r < 16; ++r) { \
    float c0 = fmaf(-2.f, sv[r], nv); \
    if (c0 < bc[r]) { bc[r] = c0; bk[r] = colT; } } }

// dbuf pipeline round, ONE barrier per tile:
//  iter T: store tile T+1 into buf^1 (its last readers finished at T-1's barrier),
//  prefetch T+2, compute T from buf, barrier (drains reads of buf before T+1 overwrites it).
#define ROUND_T(T) { \
  if ((T) < 29) { \
    STORE_T(((T) + 1) & 1); \
    const int TN = ((T) + 2 <= 29) ? (T) + 2 : 29; \
    PF_T(TN); \
  } \
  COMPUTE_T(T, (T) & 1) \
  __syncthreads(); }

// lex-min argmin flush for one dict segment; reset running best
#define FLUSH1(DICTID, BASE) { \
  _Pragma("unroll") \
  for (int r = 0; r < 16; ++r) { \
    float b0 = bc[r]; int K0 = bk[r]; \
    _Pragma("unroll") \
    for (int m = 1; m <= 16; m <<= 1) { \
      float pb = __shfl_xor(b0, m); int pk = __shfl_xor(K0, m); \
      if (pb < b0 || (pb == b0 && pk < K0)) { b0 = pb; K0 = pk; } } \
    if ((l & 31) == 0) { \
      const int ro = (r & 3) + 8 * (r >> 2) + 4 * hl; \
      keys[((rowbase + ro) << 2) | (DICTID)] = K0 - (BASE); } \
    bc[r] = 1e30f; bk[r] = 0; } }

// ---- kernel 2: MFMA scoring. 512 blocks x 256 thr: 4 waves, 128 rows, ALL 30 tiles ----
__global__ __launch_bounds__(256, 2) void vq_mfma(
    const float* __restrict__ x,
    const bf8v* __restrict__ Bph, const bf8v* __restrict__ Bpl,
    const float* __restrict__ nrm_g, int* __restrict__ keys)
{
  __shared__ bf8v BL[2][1024];   // 32 KB double-buffered B tile (hi @0..511, lo @512..1023)

  const int t = threadIdx.x;
  const int w = t >> 6, l = t & 63;
  const int hl = l >> 5;
  const int rowbase = blockIdx.x * 128 + w * 32;

  // A fragments straight from global: row = rowbase + (l&31), k0 = 16c + 8*hl
  bf8v Ah[8], Al[8];
  {
    const float* __restrict__ xr = x + (size_t)(rowbase + (l & 31)) * CDIM + hl * 8;
    #pragma unroll
    for (int c = 0; c < 8; ++c) {
      float4 u0 = *(const float4*)(xr + c * 16);
      float4 u1 = *(const float4*)(xr + c * 16 + 4);
      MK8(u0, u1, Ah[c], Al[c])
    }
  }

  f32x16 zero16;
  #pragma unroll
  for (int i = 0; i < 16; ++i) zero16[i] = 0.f;

  float bc[16]; int bk[16];
  #pragma unroll
  for (int r = 0; r < 16; ++r) { bc[r] = 1e30f; bk[r] = 0; }

  bf8v pf0, pf1, pf2, pf3;
  PF_T(0)
  STORE_T(0)
  PF_T(1)
  __syncthreads();

  // dict boundaries at tiles {2,6,14,30}
  ROUND_T(0) ROUND_T(1)
  FLUSH1(0, 0)
  for (int T = 2; T < 6; ++T) ROUND_T(T)
  FLUSH1(1, 64)
  for (int T = 6; T < 14; ++T) ROUND_T(T)
  FLUSH1(2, 192)
  for (int T = 14; T < 30; ++T) ROUND_T(T)
  FLUSH1(3, 448)
}

// ---- kernel 3: gather winners (float4, coalesced via DT), write out + loss partials ----
// 2048 blocks x 256 thr: 32 rows/block, 4 float4 per thread.
__global__ __launch_bounds__(256, 8) void vq_merge(
    const float* __restrict__ x, const float* __restrict__ DT,
    const int* __restrict__ keys,
    const float* __restrict__ alpha_p, const float* __restrict__ gamma_p,
    float* __restrict__ out, float* __restrict__ partials)
{
  __shared__ int kk[32][4];
  __shared__ float wr[4];
  const int t = threadIdx.x;
  const int row0 = blockIdx.x * 32;
  if (t < 128) {
    int r = t >> 2, d = t & 3;
    kk[r][d] = keys[((row0 + r) << 2) | d];
  }
  __syncthreads();
  const float a = alpha_p[0];
  const float g0 = gamma_p[0], g1 = gamma_p[1], g2 = gamma_p[2], g3 = gamma_p[3];
  float lc = 0.f;
  #pragma unroll
  for (int j = 0; j < 4; ++j) {
    const int f = j * 256 + t;              // 0..1023 float4 slots
    const int r = f >> 5, c4 = (f & 31) * 4;
    const size_t off = (size_t)(row0 + r) * CDIM + c4;
    const float4 xv = *(const float4*)(x + off);
    const float4 d0 = *(const float4*)(DT +         kk[r][0] * 128 + c4);
    const float4 d1 = *(const float4*)(DT +  8192 + kk[r][1] * 128 + c4);
    const float4 d2 = *(const float4*)(DT + 24576 + kk[r][2] * 128 + c4);
    const float4 d3 = *(const float4*)(DT + 57344 + kk[r][3] * 128 + c4);
    float4 o;
    o.x = a * (g0*d0.x + g1*d1.x + g2*d2.x + g3*d3.x);
    o.y = a * (g0*d0.y + g1*d1.y + g2*d2.y + g3*d3.y);
    o.z = a * (g0*d0.z + g1*d1.z + g2*d2.z + g3*d3.z);
    o.w = a * (g0*d0.w + g1*d1.w + g2*d2.w + g3*d3.w);
    *(float4*)(out + off) = o;
    float e0, e1, e2, e3;
    e0 = fmaf(-a, d0.x, xv.x); e1 = fmaf(-a, d1.x, xv.x);
    e2 = fmaf(-a, d2.x, xv.x); e3 = fmaf(-a, d3.x, xv.x);
    lc += g0*e0*e0 + g1*e1*e1 + g2*e2*e2 + g3*e3*e3;
    e0 = fmaf(-a, d0.y, xv.y); e1 = fmaf(-a, d1.y, xv.y);
    e2 = fmaf(-a, d2.y, xv.y); e3 = fmaf(-a, d3.y, xv.y);
    lc += g0*e0*e0 + g1*e1*e1 + g2*e2*e2 + g3*e3*e3;
    e0 = fmaf(-a, d0.z, xv.z); e1 = fmaf(-a, d1.z, xv.z);
    e2 = fmaf(-a, d2.z, xv.z); e3 = fmaf(-a, d3.z, xv.z);
    lc += g0*e0*e0 + g1*e1*e1 + g2*e2*e2 + g3*e3*e3;
    e0 = fmaf(-a, d0.w, xv.w); e1 = fmaf(-a, d1.w, xv.w);
    e2 = fmaf(-a, d2.w, xv.w); e3 = fmaf(-a, d3.w, xv.w);
    lc += g0*e0*e0 + g1*e1*e1 + g2*e2*e2 + g3*e3*e3;
  }
  #pragma unroll
  for (int off2 = 32; off2 > 0; off2 >>= 1) lc += __shfl_down(lc, off2);
  if ((t & 63) == 0) wr[t >> 6] = lc;
  __syncthreads();
  if (t == 0) partials[blockIdx.x] = wr[0] + wr[1] + wr[2] + wr[3];
}

// ---- kernel 4: final deterministic loss reduction (2048 partials) ----
__global__ void vq_loss(const float* __restrict__ partials, float* __restrict__ lossp) {
  __shared__ float wr[4];
  const int t = threadIdx.x;
  float v = 0.f;
  #pragma unroll
  for (int i = 0; i < 8; ++i) v += partials[i * 256 + t];
  #pragma unroll
  for (int off = 32; off > 0; off >>= 1) v += __shfl_down(v, off);
  if ((t & 63) == 0) wr[t >> 6] = v;
  __syncthreads();
  if (t == 0) lossp[0] = (wr[0] + wr[1] + wr[2] + wr[3]) * (1.25f / 8388608.f);
}

extern "C" void kernel_launch(void* const* d_in, const int* in_sizes, int n_in,
                              void* d_out, int out_size, void* d_ws, size_t ws_size,
                              hipStream_t stream) {
  const float* x  = (const float*)d_in[0];
  const float* D0 = (const float*)d_in[1];
  const float* D1 = (const float*)d_in[2];
  const float* D2 = (const float*)d_in[3];
  const float* D3 = (const float*)d_in[4];
  const float* alpha = (const float*)d_in[5];
  const float* gamma = (const float*)d_in[6];
  float* out = (float*)d_out;

  float* ws  = (float*)d_ws;
  float* nrm = ws;                         // 1024
  float* DT  = ws + 1024;                  // 122880
  bf8v*  Bph = (bf8v*)(ws + 123904);       // 61440 floats
  bf8v*  Bpl = (bf8v*)(ws + 185344);       // 61440 floats
  int*  keys = (int*)(ws + 246784);        // 262144 ints
  float* partials = ws + 508928;           // 2048

  vq_prep<<<4, 256, 0, stream>>>(D0, D1, D2, D3, nrm, DT);
  vq_pack<<<60, 256, 0, stream>>>(D0, D1, D2, D3, Bph, Bpl);
  vq_mfma<<<512, 256, 0, stream>>>(x, Bph, Bpl, nrm, keys);
  vq_merge<<<2048, 256, 0, stream>>>(x, DT, keys, alpha, gamma, out, partials);
  vq_loss<<<1, 256, 0, stream>>>(partials, out + NC);
}